// Round 1
// baseline (444.640 us; speedup 1.0000x reference)
//
#include <hip/hip_runtime.h>
#include <stdint.h>

#define Q_MAX_F 127.0f
#define EPS_F 1e-7f

typedef int   v4i __attribute__((ext_vector_type(4)));
typedef float v4f __attribute__((ext_vector_type(4)));

// ---------------------------------------------------------------------------
// Kernel 1: per-row dynamic symmetric quantization of x (fp32 -> int8)
// One block (256 threads) per row; K must be 4096 (4 chunks of 1024 floats).
// ---------------------------------------------------------------------------
__global__ __launch_bounds__(256) void quant_x_kernel(
    const float* __restrict__ x, int8_t* __restrict__ xq,
    float* __restrict__ xscale, int K) {
  const int row = blockIdx.x;
  const int t = threadIdx.x;
  const float* xr = x + (size_t)row * K;

  float v[16];
  float m = 0.f;
#pragma unroll
  for (int c = 0; c < 4; ++c) {
    v4f f = *(const v4f*)(xr + c * 1024 + t * 4);
#pragma unroll
    for (int j = 0; j < 4; ++j) {
      v[c * 4 + j] = f[j];
      m = fmaxf(m, fabsf(f[j]));
    }
  }
  // wave reduce (64 lanes)
#pragma unroll
  for (int off = 32; off; off >>= 1) m = fmaxf(m, __shfl_xor(m, off));
  __shared__ float sm[4];
  if ((t & 63) == 0) sm[t >> 6] = m;
  __syncthreads();
  m = fmaxf(fmaxf(sm[0], sm[1]), fmaxf(sm[2], sm[3]));

  const float s = fmaxf(m, EPS_F) / Q_MAX_F;
  if (t == 0) xscale[row] = s;

  int* xqi = (int*)xq;
#pragma unroll
  for (int c = 0; c < 4; ++c) {
    int packed = 0;
#pragma unroll
    for (int j = 0; j < 4; ++j) {
      float q = rintf(v[c * 4 + j] / s);          // exact div + RNE, matches jnp
      q = fminf(fmaxf(q, -127.f), 127.f);
      int qi = (int)q;
      packed |= (qi & 0xff) << (8 * j);
    }
    xqi[(size_t)row * (K / 4) + c * 256 + t] = packed;
  }
}

// ---------------------------------------------------------------------------
// Kernel 2: weight int32 -> int8 pack (values already in [-127,127])
// ---------------------------------------------------------------------------
__global__ __launch_bounds__(256) void pack_w_kernel(
    const int* __restrict__ w, int8_t* __restrict__ wq, long n4) {
  long i = (long)blockIdx.x * 256 + threadIdx.x;  // one int4 (4 ints) per thread
  if (i >= n4) return;
  v4i a = ((const v4i*)w)[i];
  int packed = (a[0] & 0xff) | ((a[1] & 0xff) << 8) |
               ((a[2] & 0xff) << 16) | ((a[3] & 0xff) << 24);
  ((int*)wq)[i] = packed;
}

// ---------------------------------------------------------------------------
// Kernel 3: int8 GEMM, C[m][n] = sum_k xq[m][k]*wq[n][k]  (both K-contiguous)
// 128x128 tile, BK=64, 4 waves (2x2), each wave 64x64 = 4x4 MFMA 16x16x64 i8.
// global_load_lds width-16 staging; LDS chunk-XOR swizzle (both-sides, rule 21).
// Fused epilogue: out = acc * xscale[m]*wscale[n] + bias[n].
// ---------------------------------------------------------------------------
#define BM 128
#define BN 128
#define BKB 64  // K-bytes per step (int8)

__global__ __launch_bounds__(256) void w8a8_gemm_kernel(
    const int8_t* __restrict__ xq, const int8_t* __restrict__ wq,
    const float* __restrict__ xscale, const float* __restrict__ wscale,
    const float* __restrict__ bias, float* __restrict__ out,
    int M, int N, int K) {
  __shared__ __align__(16) char lds[2][2 * BM * BKB];  // per buf: A[8KB] | B[8KB]

  const int t = threadIdx.x;
  const int lane = t & 63;
  const int wid = t >> 6;

  // XCD-aware bijective swizzle (nwg = 2048, divisible by 8)
  const int nwg = gridDim.x;
  int bid = blockIdx.x;
  int wg = ((nwg & 7) == 0) ? ((bid & 7) * (nwg >> 3) + (bid >> 3)) : bid;

  const int nbn = N / BN;
  const int bm = (wg / nbn) * BM;
  const int bn = (wg % nbn) * BN;

  const int wm = (wid >> 1) * 64;  // wave sub-tile offset (rows)
  const int wn = (wid & 1) * 64;   // (cols)

  v4i acc[4][4] = {};

  const char* gA = (const char*)xq + (size_t)bm * K;
  const char* gB = (const char*)wq + (size_t)bn * K;

  // Stage one 128x64 A tile + 128x64 B tile into ldsbuf.
  // 16 wave-issues of 1024B; wave w handles issues w*4..w*4+3.
  // LDS dest linear; global source pre-inverse-swizzled: chunk ^= (row>>1)&3.
  auto stage = [&](char* buf, int k0) {
#pragma unroll
    for (int j = 0; j < 4; ++j) {
      const int q = wid * 4 + j;     // 0..15, wave-uniform
      const int part = q >> 3;       // 0 = A, 1 = B
      const int qq = q & 7;
      const int lin = qq * 1024 + lane * 16;
      const int row = lin >> 6;
      const int cp = (lin >> 4) & 3;
      const int c = cp ^ ((row >> 1) & 3);
      const char* src = (part ? gB : gA) + (size_t)row * K + k0 + c * 16;
      char* dst = buf + part * 8192 + qq * 1024;  // wave-uniform base
      __builtin_amdgcn_global_load_lds(
          (const __attribute__((address_space(1))) void*)src,
          (__attribute__((address_space(3))) void*)dst, 16, 0, 0);
    }
  };

  const int NT = K / BKB;
  int cur = 0;
  stage(lds[0], 0);
  __syncthreads();

  for (int tk = 0; tk < NT; ++tk) {
    if (tk + 1 < NT) stage(lds[cur ^ 1], (tk + 1) * BKB);

    const char* bufA = lds[cur];
    const char* bufB = lds[cur] + 8192;
    const int chunk = lane >> 4;
    const int rl = lane & 15;

    v4i a[4], b[4];
#pragma unroll
    for (int i = 0; i < 4; ++i) {
      int row = wm + i * 16 + rl;
      int addr = row * 64 + ((chunk ^ ((row >> 1) & 3)) << 4);
      a[i] = *(const v4i*)(bufA + addr);
    }
#pragma unroll
    for (int i = 0; i < 4; ++i) {
      int row = wn + i * 16 + rl;
      int addr = row * 64 + ((chunk ^ ((row >> 1) & 3)) << 4);
      b[i] = *(const v4i*)(bufB + addr);
    }
#pragma unroll
    for (int i = 0; i < 4; ++i)
#pragma unroll
      for (int j = 0; j < 4; ++j)
        acc[i][j] = __builtin_amdgcn_mfma_i32_16x16x64_i8(a[i], b[j], acc[i][j], 0, 0, 0);

    __syncthreads();  // drains vmcnt (stage t+1 done) + protects buf reuse
    cur ^= 1;
  }

  // Epilogue: C/D layout col = lane&15, row = (lane>>4)*4 + reg  [m89/m101]
  const int r0 = (lane >> 4) * 4;
  const int cn = lane & 15;
#pragma unroll
  for (int i = 0; i < 4; ++i) {
    const int growb = bm + wm + i * 16 + r0;
#pragma unroll
    for (int j = 0; j < 4; ++j) {
      const int gcol = bn + wn + j * 16 + cn;
      const float wsc = wscale[gcol];
      const float bs = bias[gcol];
#pragma unroll
      for (int r = 0; r < 4; ++r) {
        const int grow = growb + r;
        const float xs = xscale[grow];
        out[(size_t)grow * N + gcol] = (float)acc[i][j][r] * (xs * wsc) + bs;
      }
    }
  }
}

// ---------------------------------------------------------------------------
extern "C" void kernel_launch(void* const* d_in, const int* in_sizes, int n_in,
                              void* d_out, int out_size, void* d_ws, size_t ws_size,
                              hipStream_t stream) {
  const float* x = (const float*)d_in[0];
  const int* w = (const int*)d_in[1];
  const float* wscale = (const float*)d_in[2];
  const float* bias = (const float*)d_in[3];
  float* out = (float*)d_out;

  const int N = in_sizes[2];                 // 4096
  const long wk = (long)in_sizes[1];         // N*K
  const int K = (int)(wk / N);               // 4096
  const int M = (int)((long)in_sizes[0] / K);// 8192

  int8_t* xq = (int8_t*)d_ws;                                  // M*K bytes
  int8_t* wq = xq + (size_t)M * K;                             // N*K bytes
  float* xscale = (float*)(wq + (size_t)N * K);                // M floats

  quant_x_kernel<<<M, 256, 0, stream>>>(x, xq, xscale, K);

  const long n4 = (long)N * K / 4;
  pack_w_kernel<<<(int)((n4 + 255) / 256), 256, 0, stream>>>(w, wq, n4);

  const int nwg = (M / BM) * (N / BN);       // 64*32 = 2048
  w8a8_gemm_kernel<<<nwg, 256, 0, stream>>>(xq, wq, xscale, wscale, bias, out,
                                            M, N, K);
}

// Round 3
// 398.699 us; speedup vs baseline: 1.1152x; 1.1152x over previous
//
#include <hip/hip_runtime.h>
#include <stdint.h>

#define Q_MAX_F 127.0f
#define EPS_F 1e-7f

typedef int   v4i __attribute__((ext_vector_type(4)));
typedef float v4f __attribute__((ext_vector_type(4)));

// ---------------------------------------------------------------------------
// Kernel 1: per-row dynamic symmetric quantization of x (fp32 -> int8)
// One block (256 threads) per row, K=4096. Reciprocal-multiply instead of
// 16 IEEE divisions per thread (div sequence = v_div_scale/fmas + s_setreg).
// ---------------------------------------------------------------------------
__global__ __launch_bounds__(256) void quant_x_kernel(
    const float* __restrict__ x, int8_t* __restrict__ xq,
    float* __restrict__ xscale, int K) {
  const int row = blockIdx.x;
  const int t = threadIdx.x;
  const float* xr = x + (size_t)row * K;

  float v[16];
  float m = 0.f;
#pragma unroll
  for (int c = 0; c < 4; ++c) {
    v4f f = *(const v4f*)(xr + c * 1024 + t * 4);
#pragma unroll
    for (int j = 0; j < 4; ++j) {
      v[c * 4 + j] = f[j];
      m = fmaxf(m, fabsf(f[j]));
    }
  }
#pragma unroll
  for (int off = 32; off; off >>= 1) m = fmaxf(m, __shfl_xor(m, off));
  __shared__ float sm[4];
  if ((t & 63) == 0) sm[t >> 6] = m;
  __syncthreads();
  m = fmaxf(fmaxf(sm[0], sm[1]), fmaxf(sm[2], sm[3]));

  const float s = fmaxf(m, EPS_F) / Q_MAX_F;   // exact, matches reference scale
  const float inv = 1.0f / s;                  // one div; then multiply
  if (t == 0) xscale[row] = s;

  int* xqi = (int*)xq;
#pragma unroll
  for (int c = 0; c < 4; ++c) {
    int packed = 0;
#pragma unroll
    for (int j = 0; j < 4; ++j) {
      float q = rintf(v[c * 4 + j] * inv);     // RNE, ~= x/s within 1 ulp
      q = fminf(fmaxf(q, -127.f), 127.f);
      packed |= ((int)q & 0xff) << (8 * j);
    }
    xqi[(size_t)row * (K / 4) + c * 256 + t] = packed;
  }
}

// ---------------------------------------------------------------------------
// Kernel 2: weight int32 -> int8 pack
// ---------------------------------------------------------------------------
__global__ __launch_bounds__(256) void pack_w_kernel(
    const int* __restrict__ w, int8_t* __restrict__ wq, long n4) {
  long i = (long)blockIdx.x * 256 + threadIdx.x;
  if (i >= n4) return;
  v4i a = ((const v4i*)w)[i];
  int packed = (a[0] & 0xff) | ((a[1] & 0xff) << 8) |
               ((a[2] & 0xff) << 16) | ((a[3] & 0xff) << 24);
  ((int*)wq)[i] = packed;
}

// ---------------------------------------------------------------------------
// Kernel 3: int8 GEMM, 256x256 tile, 8 waves (2Mx4N), each wave 128x64.
// BK=64 bytes (one mfma_i32_16x16x64_i8 K-step). 4-buffer LDS rotation
// (4 x 32KB = 128KB): group kt reads buf[kt&3]; stages K-tile kt+3 into
// buf[(kt+3)&3] = buf[(kt-1)&3], whose readers all finished before the
// group-(kt-1)-end barrier -> race-free by construction.
// Counted vmcnt(8) BEFORE the group-end barrier: every wave waits for its
// own share of K-tile kt+1's loads, then the barrier publishes them to all
// waves. Never drains to 0 in steady state (T3+T4); setprio around MFMA (T5).
// LDS chunk swizzle c^=(row>>1)&3 (verified 0 bank conflicts in round 1),
// applied to BOTH the global source of global_load_lds and the ds_read addr.
// ---------------------------------------------------------------------------
#define BM 256
#define BN 256

__global__ __launch_bounds__(512, 2) void w8a8_gemm_kernel(
    const int8_t* __restrict__ xq, const int8_t* __restrict__ wq,
    const float* __restrict__ xscale, const float* __restrict__ wscale,
    const float* __restrict__ bias, float* __restrict__ out,
    int M, int N, int K) {
  extern __shared__ char lds[];  // 4 bufs x (A 16KB | B 16KB) = 128 KB

  const int t = threadIdx.x;
  const int lane = t & 63;
  const int wid = t >> 6;     // 0..7
  const int wr = wid >> 2;    // 0..1 -> rows [wr*128, +128)
  const int wc = wid & 3;     // 0..3 -> cols [wc*64, +64)

  const int nwg = gridDim.x;
  int bid = blockIdx.x;
  int wg = ((nwg & 7) == 0) ? ((bid & 7) * (nwg >> 3) + (bid >> 3)) : bid;

  const int nbn = N / BN;
  const int bm = (wg / nbn) * BM;
  const int bn = (wg % nbn) * BN;

  const char* gA = (const char*)xq + (size_t)bm * K;
  const char* gB = (const char*)wq + (size_t)bn * K;

  v4i acc[8][4] = {};

  // Stage part p (0=A rows, 1=B rows) of K-tile kt: 256 rows x 64B = 16KB,
  // 2 global_load_lds per wave (each: wave-uniform LDS base + lane*16).
  auto stage_part = [&](int kt, int p) {
    const char* gsrc = p ? gB : gA;
    char* dstbase = lds + (size_t)(kt & 3) * 32768 + p * 16384;
#pragma unroll
    for (int i = 0; i < 2; ++i) {
      const int lin = i * 8192 + wid * 1024 + lane * 16;
      const int row = lin >> 6;                    // 0..255
      const int cs = (lane & 3) ^ ((row >> 1) & 3);  // inverse-swizzled source
      const char* src = gsrc + (size_t)row * K + kt * 64 + cs * 16;
      __builtin_amdgcn_global_load_lds(
          (const __attribute__((address_space(1))) void*)src,
          (__attribute__((address_space(3))) void*)(dstbase + i * 8192 + wid * 1024),
          16, 0, 0);
    }
  };

  const int NT = K / 64;  // 64 K-tiles
  const int rl = lane & 15;
  const int ck = lane >> 4;  // 16B k-chunk 0..3

  // Prologue: stage K-tiles 0,1,2; publish kt0 via own-vmcnt + barrier.
  for (int kt = 0; kt < 3; ++kt) { stage_part(kt, 0); stage_part(kt, 1); }
  asm volatile("s_waitcnt vmcnt(8)" ::: "memory");  // own kt0 parts landed
  asm volatile("s_barrier" ::: "memory");           // all waves' kt0 landed

  for (int kt = 0; kt < NT; ++kt) {
    const char* bufA = lds + (size_t)(kt & 3) * 32768;
    const char* bufB = bufA + 16384;

    // ---- phase 0: row-frags 0..3 x all 4 col-frags --------------------
    v4i b[4], a[4];
#pragma unroll
    for (int j = 0; j < 4; ++j) {
      const int r = wc * 64 + j * 16 + rl;
      b[j] = *(const v4i*)(bufB + r * 64 + ((ck ^ ((r >> 1) & 3)) << 4));
    }
#pragma unroll
    for (int i = 0; i < 4; ++i) {
      const int r = wr * 128 + i * 16 + rl;
      a[i] = *(const v4i*)(bufA + r * 64 + ((ck ^ ((r >> 1) & 3)) << 4));
    }
    if (kt + 3 < NT) stage_part(kt + 3, 0);
    __builtin_amdgcn_s_setprio(1);
#pragma unroll
    for (int i = 0; i < 4; ++i)
#pragma unroll
      for (int j = 0; j < 4; ++j)
        acc[i][j] = __builtin_amdgcn_mfma_i32_16x16x64_i8(a[i], b[j], acc[i][j], 0, 0, 0);
    __builtin_amdgcn_s_setprio(0);
    asm volatile("s_barrier" ::: "memory");  // phase separator (same buf)

    // ---- phase 1: row-frags 4..7, reuse b[] ---------------------------
#pragma unroll
    for (int i = 0; i < 4; ++i) {
      const int r = wr * 128 + 64 + i * 16 + rl;
      a[i] = *(const v4i*)(bufA + r * 64 + ((ck ^ ((r >> 1) & 3)) << 4));
    }
    if (kt + 3 < NT) stage_part(kt + 3, 1);
    __builtin_amdgcn_s_setprio(1);
#pragma unroll
    for (int i = 0; i < 4; ++i)
#pragma unroll
      for (int j = 0; j < 4; ++j)
        acc[4 + i][j] = __builtin_amdgcn_mfma_i32_16x16x64_i8(a[i], b[j], acc[4 + i][j], 0, 0, 0);
    __builtin_amdgcn_s_setprio(0);

    // Group-end: wait (own loads for kt+1) BEFORE barrier -> barrier
    // publishes every wave's landed loads to all readers of group kt+1.
    if (kt <= NT - 4)      asm volatile("s_waitcnt vmcnt(8)" ::: "memory");
    else if (kt == NT - 3) asm volatile("s_waitcnt vmcnt(4)" ::: "memory");
    else if (kt == NT - 2) asm volatile("s_waitcnt vmcnt(0)" ::: "memory");
    asm volatile("s_barrier" ::: "memory");
  }

  // Epilogue: C/D layout col = lane&15, row = (lane>>4)*4 + reg.
  const int r0 = (lane >> 4) * 4;
  const int cn = lane & 15;
#pragma unroll
  for (int i = 0; i < 8; ++i) {
    const int growb = bm + wr * 128 + i * 16 + r0;
#pragma unroll
    for (int j = 0; j < 4; ++j) {
      const int gcol = bn + wc * 64 + j * 16 + cn;
      const float wsc = wscale[gcol];
      const float bs = bias[gcol];
#pragma unroll
      for (int r = 0; r < 4; ++r) {
        const int grow = growb + r;
        const float xs = xscale[grow];
        out[(size_t)grow * N + gcol] = (float)acc[i][j][r] * (xs * wsc) + bs;
      }
    }
  }
}

// ---------------------------------------------------------------------------
extern "C" void kernel_launch(void* const* d_in, const int* in_sizes, int n_in,
                              void* d_out, int out_size, void* d_ws, size_t ws_size,
                              hipStream_t stream) {
  const float* x = (const float*)d_in[0];
  const int* w = (const int*)d_in[1];
  const float* wscale = (const float*)d_in[2];
  const float* bias = (const float*)d_in[3];
  float* out = (float*)d_out;

  const int N = in_sizes[2];                  // 4096
  const long wk = (long)in_sizes[1];          // N*K
  const int K = (int)(wk / N);                // 4096
  const int M = (int)((long)in_sizes[0] / K); // 8192

  int8_t* xq = (int8_t*)d_ws;                       // M*K
  int8_t* wq = xq + (size_t)M * K;                  // N*K
  float* xscale = (float*)(wq + (size_t)N * K);     // M floats

  quant_x_kernel<<<M, 256, 0, stream>>>(x, xq, xscale, K);

  const long n4 = (long)N * K / 4;
  pack_w_kernel<<<(int)((n4 + 255) / 256), 256, 0, stream>>>(w, wq, n4);

  const int nwg = (M / BM) * (N / BN);  // 32*16 = 512
  w8a8_gemm_kernel<<<nwg, 512, 131072, stream>>>(xq, wq, xscale, wscale, bias,
                                                 out, M, N, K);
}